// Round 1
// baseline (1338.088 us; speedup 1.0000x reference)
//
#include <hip/hip_runtime.h>

// Problem constants (fixed by the reference)
constexpr int NN  = 50000;
constexpr int DIN = 7;
constexpr int EE  = 800000;
constexpr int DD  = 64;
constexpr int LL  = 3;
constexpr int GG  = 64;

__device__ __forceinline__ float reluf(float x) { return x > 0.f ? x : 0.f; }

// ---------------- edge pass 1: in-degree count + node+edge feature sums ----
__global__ void k_edge1(const int* __restrict__ ei, const float* __restrict__ x,
                        const float* __restrict__ ea,
                        int* __restrict__ cnt, float* __restrict__ ne_sum) {
    int e = blockIdx.x * blockDim.x + threadIdx.x;
    if (e >= EE) return;
    int col = ei[e];        // source
    int row = ei[EE + e];   // destination
    atomicAdd(&cnt[row], 1);
    float* dst = ne_sum + (size_t)row * 8;
#pragma unroll
    for (int f = 0; f < 7; f++) unsafeAtomicAdd(&dst[f], x[col * 7 + f]);
    unsafeAtomicAdd(&dst[7], ea[e]);
}

// ---------------- per-graph degree max (degree >= 0 so uint-bit max works) -
__global__ void k_degmax(const int* __restrict__ batch, const float* __restrict__ degree,
                         unsigned* __restrict__ degmax_u) {
    int i = blockIdx.x * blockDim.x + threadIdx.x;
    if (i >= NN) return;
    atomicMax(&degmax_u[batch[i]], __float_as_uint(degree[i]));
}

// ---------------- exclusive scan of cnt -> off (single block) --------------
__global__ void k_scan(const int* __restrict__ cnt, int* __restrict__ off) {
    __shared__ int buf[1024];
    __shared__ int carry_s;
    int t = threadIdx.x;
    if (t == 0) carry_s = 0;
    __syncthreads();
    for (int base = 0; base < NN; base += 1024) {
        int i = base + t;
        int v = (i < NN) ? cnt[i] : 0;
        buf[t] = v;
        __syncthreads();
        for (int s = 1; s < 1024; s <<= 1) {
            int addend = (t >= s) ? buf[t - s] : 0;
            __syncthreads();
            buf[t] += addend;
            __syncthreads();
        }
        int incl = buf[t];
        int carry = carry_s;
        if (i < NN) off[i] = carry + incl - v;
        __syncthreads();
        if (t == 1023) carry_s = carry + incl;
        __syncthreads();
    }
    if (t == 0) off[NN] = carry_s;
}

// ---------------- edge pass 2: scatter edges into CSR order ----------------
__global__ void k_fill(const int* __restrict__ ei, const float* __restrict__ ea,
                       const int* __restrict__ off, int* __restrict__ fill,
                       int2* __restrict__ sorted) {
    int e = blockIdx.x * blockDim.x + threadIdx.x;
    if (e >= EE) return;
    int col = ei[e];
    int row = ei[EE + e];
    int p = off[row] + atomicAdd(&fill[row], 1);
    sorted[p] = make_int2(col, __float_as_int(ea[e]));
}

// ---------------- node embeddings: x_emb and x_agg_emb ---------------------
__global__ __launch_bounds__(256) void k_node_embed(
        const float* __restrict__ x, const int* __restrict__ cnt,
        const float* __restrict__ ne_sum, const unsigned* __restrict__ degmax_u,
        const int* __restrict__ batch,
        const float* __restrict__ W_en, const float* __restrict__ b_en,
        const float* __restrict__ W_ene, const float* __restrict__ b_ene,
        const float* __restrict__ W_agg, const float* __restrict__ b_agg,
        float* __restrict__ x_emb, float* __restrict__ x_agg_emb) {
    __shared__ float sWen[7 * 64], sben[64];
    __shared__ float sWene[8 * 63], sbene[63];
    __shared__ float sWagg[64 * 64], sbagg[64];
    __shared__ float sin[4 * 64];
    for (int i = threadIdx.x; i < 7 * 64; i += 256) sWen[i] = W_en[i];
    for (int i = threadIdx.x; i < 64; i += 256) sben[i] = b_en[i];
    for (int i = threadIdx.x; i < 8 * 63; i += 256) sWene[i] = W_ene[i];
    for (int i = threadIdx.x; i < 63; i += 256) sbene[i] = b_ene[i];
    for (int i = threadIdx.x; i < 64 * 64; i += 256) sWagg[i] = W_agg[i];
    for (int i = threadIdx.x; i < 64; i += 256) sbagg[i] = b_agg[i];
    __syncthreads();
    int lane = threadIdx.x & 63;
    int slot = threadIdx.x >> 6;
    int wave = blockIdx.x * 4 + slot;
    int nw = gridDim.x * 4;
    for (int i = wave; i < NN; i += nw) {
        // x_emb = relu(x @ W_en + b_en)
        float acc = sben[lane];
#pragma unroll
        for (int k = 0; k < 7; k++) acc += x[i * 7 + k] * sWen[k * 64 + lane];
        x_emb[(size_t)i * 64 + lane] = reluf(acc);
        // node_edge mean -> relu(@ W_ene + b_ene), then append degree_norm
        float c = (float)cnt[i]; if (c < 1.f) c = 1.f;
        float rc = 1.f / c;
        int oo = lane < 63 ? lane : 0;
        float na = sbene[oo];
#pragma unroll
        for (int k = 0; k < 8; k++) na += (ne_sum[(size_t)i * 8 + k] * rc) * sWene[k * 63 + oo];
        na = reluf(na);
        float dn = __uint_as_float(degmax_u[batch[i]]);
        float v = (lane < 63) ? na : dn;
        sin[slot * 64 + lane] = v;
        float xa = sbagg[lane];
        for (int k = 0; k < 64; k++) xa += sin[slot * 64 + k] * sWagg[k * 64 + lane];
        x_agg_emb[(size_t)i * 64 + lane] = reluf(xa);
    }
}

// ---------------- layer: aggregate + m = relu([x_agg, x_agg_emb] @ Wm + bm)
__global__ __launch_bounds__(256) void k_layer_agg_m(
        const float* __restrict__ xemb, const float* __restrict__ x_agg_emb,
        const int* __restrict__ off, const int* __restrict__ cnt,
        const int2* __restrict__ sorted,
        const float* __restrict__ Wm, const float* __restrict__ bm,
        float* __restrict__ m_out) {
    __shared__ float sW[128 * 64];
    __shared__ float sb[64];
    __shared__ float sin[4 * 128];
    for (int i = threadIdx.x; i < 128 * 64; i += 256) sW[i] = Wm[i];
    for (int i = threadIdx.x; i < 64; i += 256) sb[i] = bm[i];
    __syncthreads();
    int lane = threadIdx.x & 63;
    int slot = threadIdx.x >> 6;
    int wave = blockIdx.x * 4 + slot;
    int nw = gridDim.x * 4;
    for (int i = wave; i < NN; i += nw) {
        int jb = off[i], je = off[i + 1];
        float acc = 0.f;
        for (int j = jb; j < je; j++) {
            int2 p = sorted[j];
            acc += __int_as_float(p.y) * xemb[(size_t)p.x * 64 + lane];
        }
        float c = (float)cnt[i]; if (c < 1.f) c = 1.f;
        float xagg = acc * (1.f / c);
        sin[slot * 128 + lane] = xagg;
        sin[slot * 128 + 64 + lane] = x_agg_emb[(size_t)i * 64 + lane];
        float mm = sb[lane];
#pragma unroll 8
        for (int k = 0; k < 128; k++) mm += sin[slot * 128 + k] * sW[k * 64 + lane];
        m_out[(size_t)i * 64 + lane] = reluf(mm);
    }
}

// ---------------- layer: x_emb' = relu([x_emb, m] @ Wu + bu) ---------------
__global__ __launch_bounds__(256) void k_layer_upd(
        const float* __restrict__ xemb_old, const float* __restrict__ m_in,
        const float* __restrict__ Wu, const float* __restrict__ bu,
        float* __restrict__ xemb_new) {
    __shared__ float sW[128 * 64];
    __shared__ float sb[64];
    __shared__ float sin[4 * 128];
    for (int i = threadIdx.x; i < 128 * 64; i += 256) sW[i] = Wu[i];
    for (int i = threadIdx.x; i < 64; i += 256) sb[i] = bu[i];
    __syncthreads();
    int lane = threadIdx.x & 63;
    int slot = threadIdx.x >> 6;
    int wave = blockIdx.x * 4 + slot;
    int nw = gridDim.x * 4;
    for (int i = wave; i < NN; i += nw) {
        sin[slot * 128 + lane] = xemb_old[(size_t)i * 64 + lane];
        sin[slot * 128 + 64 + lane] = m_in[(size_t)i * 64 + lane];
        float mm = sb[lane];
#pragma unroll 8
        for (int k = 0; k < 128; k++) mm += sin[slot * 128 + k] * sW[k * 64 + lane];
        xemb_new[(size_t)i * 64 + lane] = reluf(mm);
    }
}

// ---------------- graph mean (batch is sorted: chunked accumulation) -------
constexpr int CHUNK = 32;
__global__ void k_graph_sum(const float* __restrict__ xemb, const int* __restrict__ batch,
                            float* __restrict__ g_sum, int* __restrict__ g_cnt) {
    int wave = (blockIdx.x * blockDim.x + threadIdx.x) >> 6;
    int lane = threadIdx.x & 63;
    int i0 = wave * CHUNK;
    if (i0 >= NN) return;
    int i1 = i0 + CHUNK; if (i1 > NN) i1 = NN;
    int curb = batch[i0];
    float acc = 0.f;
    int ncnt = 0;
    for (int i = i0; i < i1; i++) {
        int b = batch[i];
        if (b != curb) {
            unsafeAtomicAdd(&g_sum[curb * 64 + lane], acc);
            if (lane == 0) atomicAdd(&g_cnt[curb], ncnt);
            acc = 0.f; ncnt = 0; curb = b;
        }
        acc += xemb[(size_t)i * 64 + lane];
        ncnt++;
    }
    unsafeAtomicAdd(&g_sum[curb * 64 + lane], acc);
    if (lane == 0) atomicAdd(&g_cnt[curb], ncnt);
}

// ---------------- graph embedding: g_agg = mean @ W_g + b_g (no relu) ------
__global__ void k_graph_emb(const float* __restrict__ g_sum, const int* __restrict__ g_cnt,
                            const float* __restrict__ W_g, const float* __restrict__ b_g,
                            float* __restrict__ g_agg) {
    __shared__ float sin[4 * 64];
    int lane = threadIdx.x & 63;
    int slot = threadIdx.x >> 6;
    int g = blockIdx.x * 4 + slot;
    if (g >= GG) return;
    float c = (float)g_cnt[g]; if (c < 1.f) c = 1.f;
    sin[slot * 64 + lane] = g_sum[g * 64 + lane] * (1.f / c);
    float acc = b_g[lane];
    for (int k = 0; k < 64; k++) acc += sin[slot * 64 + k] * W_g[k * 64 + lane];
    g_agg[g * 64 + lane] = acc;  // no relu here (ref applies relu to concat later)
}

// ---------------- readout: q = relu([g_agg[batch], x_emb]) @ W_r + b_r -----
__global__ void k_readout(const float* __restrict__ g_agg, const float* __restrict__ xemb,
                          const int* __restrict__ batch,
                          const float* __restrict__ W_r, const float* __restrict__ b_r,
                          float* __restrict__ out) {
    int i = blockIdx.x * blockDim.x + threadIdx.x;
    if (i >= NN) return;
    int b = batch[i];
    float acc = b_r[0];
    const float* ga = g_agg + (size_t)b * 64;
    const float* xe = xemb + (size_t)i * 64;
#pragma unroll 8
    for (int k = 0; k < 64; k++) acc += reluf(ga[k]) * W_r[k];
#pragma unroll 8
    for (int k = 0; k < 64; k++) acc += reluf(xe[k]) * W_r[64 + k];
    out[i] = acc;
}

extern "C" void kernel_launch(void* const* d_in, const int* in_sizes, int n_in,
                              void* d_out, int out_size, void* d_ws, size_t ws_size,
                              hipStream_t stream) {
    const float* x      = (const float*)d_in[0];
    const int*   ei     = (const int*)d_in[1];
    const float* ea     = (const float*)d_in[2];
    const int*   batch  = (const int*)d_in[3];
    const float* degree = (const float*)d_in[4];
    const float* W_en  = (const float*)d_in[6];
    const float* b_en  = (const float*)d_in[7];
    const float* W_ene = (const float*)d_in[8];
    const float* b_ene = (const float*)d_in[9];
    const float* W_agg = (const float*)d_in[10];
    const float* b_agg = (const float*)d_in[11];
    const float* Wm    = (const float*)d_in[12];
    const float* bm    = (const float*)d_in[13];
    const float* Wu    = (const float*)d_in[14];
    const float* bu    = (const float*)d_in[15];
    const float* W_g   = (const float*)d_in[16];
    const float* b_g   = (const float*)d_in[17];
    const float* W_r   = (const float*)d_in[18];
    const float* b_r   = (const float*)d_in[19];
    float* out = (float*)d_out;

    // workspace layout (4B element offsets)
    char* ws = (char*)d_ws;
    size_t o = 0;
    int*      cnt      = (int*)(ws + o * 4);      o += NN;
    int*      fill     = (int*)(ws + o * 4);      o += NN;
    float*    ne_sum   = (float*)(ws + o * 4);    o += (size_t)NN * 8;
    unsigned* degmax_u = (unsigned*)(ws + o * 4); o += GG;
    float*    g_sum    = (float*)(ws + o * 4);    o += GG * 64;
    int*      g_cnt    = (int*)(ws + o * 4);      o += GG;
    size_t zero_bytes = o * 4;
    int*      off      = (int*)(ws + o * 4);      o += NN + 1;
    o = (o + 1) & ~(size_t)1;  // 8B-align for int2
    int2*     sorted   = (int2*)(ws + o * 4);     o += (size_t)EE * 2;
    float*    xA       = (float*)(ws + o * 4);    o += (size_t)NN * 64;
    float*    xB       = (float*)(ws + o * 4);    o += (size_t)NN * 64;
    float*    xae      = (float*)(ws + o * 4);    o += (size_t)NN * 64;
    float*    mbuf     = (float*)(ws + o * 4);    o += (size_t)NN * 64;
    float*    g_agg    = (float*)(ws + o * 4);    o += GG * 64;

    hipMemsetAsync(d_ws, 0, zero_bytes, stream);

    k_edge1<<<(EE + 255) / 256, 256, 0, stream>>>(ei, x, ea, cnt, ne_sum);
    k_degmax<<<(NN + 255) / 256, 256, 0, stream>>>(batch, degree, degmax_u);
    k_scan<<<1, 1024, 0, stream>>>(cnt, off);
    k_fill<<<(EE + 255) / 256, 256, 0, stream>>>(ei, ea, off, fill, sorted);
    k_node_embed<<<1024, 256, 0, stream>>>(x, cnt, ne_sum, degmax_u, batch,
                                           W_en, b_en, W_ene, b_ene, W_agg, b_agg,
                                           xA, xae);
    const float* cur = xA;
    float* nxt = xB;
    for (int l = 0; l < LL; l++) {
        k_layer_agg_m<<<1024, 256, 0, stream>>>(cur, xae, off, cnt, sorted,
                                                Wm + (size_t)l * 128 * 64, bm + l * 64, mbuf);
        k_layer_upd<<<1024, 256, 0, stream>>>(cur, mbuf,
                                              Wu + (size_t)l * 128 * 64, bu + l * 64, nxt);
        float* t = (float*)cur; cur = nxt; nxt = t;
    }
    int gs_waves = (NN + CHUNK - 1) / CHUNK;
    k_graph_sum<<<(gs_waves * 64 + 255) / 256, 256, 0, stream>>>(cur, batch, g_sum, g_cnt);
    k_graph_emb<<<16, 256, 0, stream>>>(g_sum, g_cnt, W_g, b_g, g_agg);
    k_readout<<<(NN + 255) / 256, 256, 0, stream>>>(g_agg, cur, batch, W_r, b_r, out);
}

// Round 2
// 1234.446 us; speedup vs baseline: 1.0840x; 1.0840x over previous
//
#include <hip/hip_runtime.h>

constexpr int NN  = 50000;
constexpr int EE  = 800000;
constexpr int GG  = 64;
constexpr int LL  = 3;

__device__ __forceinline__ float reluf(float x) { return x > 0.f ? x : 0.f; }

// ---------------- in-degree count --------------------------------------------
__global__ void k_count(const int* __restrict__ ei, int* __restrict__ cnt) {
    int e = blockIdx.x * blockDim.x + threadIdx.x;
    if (e >= EE) return;
    atomicAdd(&cnt[ei[EE + e]], 1);
}

// ---------------- per-graph degree max (degree >= 0 so uint-bit max works) ---
__global__ void k_degmax(const int* __restrict__ batch, const float* __restrict__ degree,
                         unsigned* __restrict__ degmax_u) {
    int i = blockIdx.x * blockDim.x + threadIdx.x;
    if (i >= NN) return;
    atomicMax(&degmax_u[batch[i]], __float_as_uint(degree[i]));
}

// ---------------- parallel exclusive scan: 49 blocks x 1024 elems ------------
__global__ void k_scan1(const int* __restrict__ cnt, int* __restrict__ off,
                        int* __restrict__ bsum) {
    __shared__ int s[256];
    int t = threadIdx.x, blk = blockIdx.x;
    int base = blk * 1024 + t * 4;
    int v[4], tot = 0;
#pragma unroll
    for (int j = 0; j < 4; j++) {
        int i = base + j;
        v[j] = (i < NN) ? cnt[i] : 0;
        tot += v[j];
    }
    s[t] = tot;
    __syncthreads();
    for (int d = 1; d < 256; d <<= 1) {
        int a = (t >= d) ? s[t - d] : 0;
        __syncthreads();
        s[t] += a;
        __syncthreads();
    }
    int run = s[t] - tot;  // exclusive prefix within block
#pragma unroll
    for (int j = 0; j < 4; j++) {
        int i = base + j;
        if (i <= NN) off[i] = run;
        run += v[j];
    }
    if (t == 255) bsum[blk] = s[255];
}
__global__ void k_scan2(int* __restrict__ bsum, int nb) {
    if (threadIdx.x == 0) {
        int run = 0;
        for (int b = 0; b < nb; b++) { int t = bsum[b]; bsum[b] = run; run += t; }
    }
}
__global__ void k_scan3(int* __restrict__ off, const int* __restrict__ bsum) {
    int i = blockIdx.x * blockDim.x + threadIdx.x;
    if (i <= NN) off[i] += bsum[i >> 10];
}

// ---------------- scatter edges into CSR order -------------------------------
__global__ void k_fill(const int* __restrict__ ei, const float* __restrict__ ea,
                       const int* __restrict__ off, int* __restrict__ fill,
                       int2* __restrict__ sorted) {
    int e = blockIdx.x * blockDim.x + threadIdx.x;
    if (e >= EE) return;
    int col = ei[e];
    int row = ei[EE + e];
    int p = off[row] + atomicAdd(&fill[row], 1);
    sorted[p] = make_int2(col, __float_as_int(ea[e]));
}

// ---------------- ne_sum from CSR (atomic-free): 8 lanes per node ------------
__global__ void k_nesum(const float* __restrict__ x, const int2* __restrict__ sorted,
                        const int* __restrict__ off, float* __restrict__ ne_sum) {
    int gwave = (blockIdx.x * blockDim.x + threadIdx.x) >> 6;
    int lane = threadIdx.x & 63;
    int sub = lane >> 3;   // 8 nodes per wave
    int f = lane & 7;      // 8 features (7 x + 1 ea)
    int node = gwave * 8 + sub;
    if (node >= NN) return;
    int jb = off[node], je = off[node + 1];
    float acc = 0.f;
    for (int j = jb; j < je; j++) {
        int2 p = sorted[j];
        acc += (f < 7) ? x[(size_t)p.x * 7 + f] : __int_as_float(p.y);
    }
    ne_sum[(size_t)node * 8 + f] = acc;
}

// ---------------- node pre: x_emb and agg_in = [relu(ne@W_ene+b), degnorm] ---
__global__ __launch_bounds__(256) void k_node_pre(
        const float* __restrict__ x, const int* __restrict__ cnt,
        const float* __restrict__ ne_sum, const unsigned* __restrict__ degmax_u,
        const int* __restrict__ batch,
        const float* __restrict__ W_en, const float* __restrict__ b_en,
        const float* __restrict__ W_ene, const float* __restrict__ b_ene,
        float* __restrict__ x_emb, float* __restrict__ agg_in) {
    __shared__ float sWen[7 * 64], sben[64];
    __shared__ float sWene[8 * 63], sbene[63];
    for (int i = threadIdx.x; i < 7 * 64; i += 256) sWen[i] = W_en[i];
    for (int i = threadIdx.x; i < 64; i += 256) sben[i] = b_en[i];
    for (int i = threadIdx.x; i < 8 * 63; i += 256) sWene[i] = W_ene[i];
    for (int i = threadIdx.x; i < 63; i += 256) sbene[i] = b_ene[i];
    __syncthreads();
    int lane = threadIdx.x & 63;
    int slot = threadIdx.x >> 6;
    int wave = blockIdx.x * 4 + slot;
    int nw = gridDim.x * 4;
    for (int i = wave; i < NN; i += nw) {
        float acc = sben[lane];
#pragma unroll
        for (int k = 0; k < 7; k++) acc += x[(size_t)i * 7 + k] * sWen[k * 64 + lane];
        x_emb[(size_t)i * 64 + lane] = reluf(acc);
        float c = (float)cnt[i]; if (c < 1.f) c = 1.f;
        float rc = 1.f / c;
        int oo = lane < 63 ? lane : 0;
        float na = sbene[oo];
#pragma unroll
        for (int k = 0; k < 8; k++) na += (ne_sum[(size_t)i * 8 + k] * rc) * sWene[k * 63 + oo];
        na = reluf(na);
        float dn = __uint_as_float(degmax_u[batch[i]]);
        agg_in[(size_t)i * 64 + lane] = (lane < 63) ? na : dn;
    }
}

// ---------------- matvec: out = relu([inA|inB] @ W + b), lane = node ---------
// wave handles 64 nodes x 32 outputs (OSPLIT=2). Weights via wave-uniform
// scalar loads (s_load) -> VALU-bound, zero LDS.
template <int K>
__global__ __launch_bounds__(256) void k_matvec(
        const float* __restrict__ inA, const float* __restrict__ inB,
        const float* __restrict__ W, const float* __restrict__ b,
        float* __restrict__ out, int n) {
    int gwave = (blockIdx.x * blockDim.x + threadIdx.x) >> 6;
    int lane = threadIdx.x & 63;
    int nwaves = (gridDim.x * blockDim.x) >> 6;
    int ntiles = ((n + 63) >> 6) * 2;
    for (int tile = gwave; tile < ntiles; tile += nwaves) {
        int base = (tile >> 1) * 64;
        int ohalf = tile & 1;
        int node = base + lane;
        bool valid = node < n;
        int nd = valid ? node : (n - 1);
        const float* pa = inA + (size_t)nd * 64;
        const float* pb = (K == 128) ? (inB + (size_t)nd * 64) : pa;
        float acc[32];
#pragma unroll
        for (int o = 0; o < 32; o++) acc[o] = 0.f;
        for (int kb = 0; kb < K; kb += 8) {
            float in[8];
            const float* src = (K == 64 || kb < 64) ? (pa + kb) : (pb + (kb - 64));
            *(float4*)&in[0] = *(const float4*)(src);
            *(float4*)&in[4] = *(const float4*)(src + 4);
#pragma unroll
            for (int kk = 0; kk < 8; kk++) {
                const float* wr = W + (size_t)(kb + kk) * 64 + ohalf * 32;
#pragma unroll
                for (int o = 0; o < 32; o++)
                    acc[o] = fmaf(in[kk], wr[o], acc[o]);
            }
        }
        if (valid) {
            const float* bb = b + ohalf * 32;
            float* po = out + (size_t)nd * 64 + ohalf * 32;
            float4 r;
#pragma unroll
            for (int o = 0; o < 32; o += 4) {
                r.x = reluf(acc[o + 0] + bb[o + 0]);
                r.y = reluf(acc[o + 1] + bb[o + 1]);
                r.z = reluf(acc[o + 2] + bb[o + 2]);
                r.w = reluf(acc[o + 3] + bb[o + 3]);
                *(float4*)(po + o) = r;
            }
        }
    }
}

// ---------------- layer aggregation: x_agg = mean_j ea_j * xemb[col_j] -------
__global__ __launch_bounds__(256) void k_layer_agg(
        const float* __restrict__ xemb, const int* __restrict__ off,
        const int* __restrict__ cnt, const int2* __restrict__ sorted,
        float* __restrict__ xagg) {
    int lane = threadIdx.x & 63;
    int slot = threadIdx.x >> 6;
    int wave = blockIdx.x * 4 + slot;
    int nw = gridDim.x * 4;
    for (int i = wave; i < NN; i += nw) {
        int jb = off[i], je = off[i + 1];
        float acc = 0.f;
        for (int j = jb; j < je; j++) {
            int2 p = sorted[j];
            acc += __int_as_float(p.y) * xemb[(size_t)p.x * 64 + lane];
        }
        float c = (float)cnt[i]; if (c < 1.f) c = 1.f;
        xagg[(size_t)i * 64 + lane] = acc * (1.f / c);
    }
}

// ---------------- graph mean (batch sorted: chunked accumulation) ------------
constexpr int CHUNK = 32;
__global__ void k_graph_sum(const float* __restrict__ xemb, const int* __restrict__ batch,
                            float* __restrict__ g_sum, int* __restrict__ g_cnt) {
    int wave = (blockIdx.x * blockDim.x + threadIdx.x) >> 6;
    int lane = threadIdx.x & 63;
    int i0 = wave * CHUNK;
    if (i0 >= NN) return;
    int i1 = i0 + CHUNK; if (i1 > NN) i1 = NN;
    int curb = batch[i0];
    float acc = 0.f;
    int ncnt = 0;
    for (int i = i0; i < i1; i++) {
        int b = batch[i];
        if (b != curb) {
            unsafeAtomicAdd(&g_sum[curb * 64 + lane], acc);
            if (lane == 0) atomicAdd(&g_cnt[curb], ncnt);
            acc = 0.f; ncnt = 0; curb = b;
        }
        acc += xemb[(size_t)i * 64 + lane];
        ncnt++;
    }
    unsafeAtomicAdd(&g_sum[curb * 64 + lane], acc);
    if (lane == 0) atomicAdd(&g_cnt[curb], ncnt);
}

// ---------------- graph embedding: g_agg = mean @ W_g + b_g (no relu) --------
__global__ void k_graph_emb(const float* __restrict__ g_sum, const int* __restrict__ g_cnt,
                            const float* __restrict__ W_g, const float* __restrict__ b_g,
                            float* __restrict__ g_agg) {
    __shared__ float sin[4 * 64];
    int lane = threadIdx.x & 63;
    int slot = threadIdx.x >> 6;
    int g = blockIdx.x * 4 + slot;
    if (g >= GG) return;
    float c = (float)g_cnt[g]; if (c < 1.f) c = 1.f;
    sin[slot * 64 + lane] = g_sum[g * 64 + lane] * (1.f / c);
    __syncthreads();
    float acc = b_g[lane];
    for (int k = 0; k < 64; k++) acc += sin[slot * 64 + k] * W_g[k * 64 + lane];
    g_agg[g * 64 + lane] = acc;
}

// ---------------- readout: q = relu([g_agg[batch], x_emb]) @ W_r + b_r -------
__global__ void k_readout(const float* __restrict__ g_agg, const float* __restrict__ xemb,
                          const int* __restrict__ batch,
                          const float* __restrict__ W_r, const float* __restrict__ b_r,
                          float* __restrict__ out) {
    int i = blockIdx.x * blockDim.x + threadIdx.x;
    if (i >= NN) return;
    int b = batch[i];
    float acc = b_r[0];
    const float* ga = g_agg + (size_t)b * 64;
    const float* xe = xemb + (size_t)i * 64;
#pragma unroll 8
    for (int k = 0; k < 64; k++) acc += reluf(ga[k]) * W_r[k];
#pragma unroll 8
    for (int k = 0; k < 64; k++) acc += reluf(xe[k]) * W_r[64 + k];
    out[i] = acc;
}

extern "C" void kernel_launch(void* const* d_in, const int* in_sizes, int n_in,
                              void* d_out, int out_size, void* d_ws, size_t ws_size,
                              hipStream_t stream) {
    const float* x      = (const float*)d_in[0];
    const int*   ei     = (const int*)d_in[1];
    const float* ea     = (const float*)d_in[2];
    const int*   batch  = (const int*)d_in[3];
    const float* degree = (const float*)d_in[4];
    const float* W_en  = (const float*)d_in[6];
    const float* b_en  = (const float*)d_in[7];
    const float* W_ene = (const float*)d_in[8];
    const float* b_ene = (const float*)d_in[9];
    const float* W_agg = (const float*)d_in[10];
    const float* b_agg = (const float*)d_in[11];
    const float* Wm    = (const float*)d_in[12];
    const float* bm    = (const float*)d_in[13];
    const float* Wu    = (const float*)d_in[14];
    const float* bu    = (const float*)d_in[15];
    const float* W_g   = (const float*)d_in[16];
    const float* b_g   = (const float*)d_in[17];
    const float* W_r   = (const float*)d_in[18];
    const float* b_r   = (const float*)d_in[19];
    float* out = (float*)d_out;

    // workspace layout (4B element offsets); zeroed region first
    char* ws = (char*)d_ws;
    size_t o = 0;
    int*      cnt      = (int*)(ws + o * 4);      o += NN;
    int*      fill     = (int*)(ws + o * 4);      o += NN;
    unsigned* degmax_u = (unsigned*)(ws + o * 4); o += GG;
    float*    g_sum    = (float*)(ws + o * 4);    o += GG * 64;
    int*      g_cnt    = (int*)(ws + o * 4);      o += GG;
    size_t zero_bytes = o * 4;
    int*      off      = (int*)(ws + o * 4);      o += NN + 1;
    int*      bsum     = (int*)(ws + o * 4);      o += 64;
    float*    ne_sum   = (float*)(ws + o * 4);    o += (size_t)NN * 8;
    o = (o + 1) & ~(size_t)1;  // 8B-align for int2
    int2*     sorted   = (int2*)(ws + o * 4);     o += (size_t)EE * 2;
    float*    agg_in   = (float*)(ws + o * 4);    o += (size_t)NN * 64;
    float*    xae      = (float*)(ws + o * 4);    o += (size_t)NN * 64;
    float*    xA       = (float*)(ws + o * 4);    o += (size_t)NN * 64;
    float*    xB       = (float*)(ws + o * 4);    o += (size_t)NN * 64;
    float*    xagg     = (float*)(ws + o * 4);    o += (size_t)NN * 64;
    float*    mbuf     = (float*)(ws + o * 4);    o += (size_t)NN * 64;
    float*    g_agg    = (float*)(ws + o * 4);    o += GG * 64;

    hipMemsetAsync(d_ws, 0, zero_bytes, stream);

    const int NB_SCAN = 49;  // ceil(50001/1024)
    k_count<<<(EE + 255) / 256, 256, 0, stream>>>(ei, cnt);
    k_degmax<<<(NN + 255) / 256, 256, 0, stream>>>(batch, degree, degmax_u);
    k_scan1<<<NB_SCAN, 256, 0, stream>>>(cnt, off, bsum);
    k_scan2<<<1, 64, 0, stream>>>(bsum, NB_SCAN);
    k_scan3<<<(NN + 256) / 256, 256, 0, stream>>>(off, bsum);
    k_fill<<<(EE + 255) / 256, 256, 0, stream>>>(ei, ea, off, fill, sorted);
    k_nesum<<<((NN + 7) / 8 * 64 + 255) / 256, 256, 0, stream>>>(x, sorted, off, ne_sum);
    k_node_pre<<<512, 256, 0, stream>>>(x, cnt, ne_sum, degmax_u, batch,
                                        W_en, b_en, W_ene, b_ene, xA, agg_in);
    const int MV_BLOCKS = 391;  // ceil(782*2/4) waves for n=50000
    k_matvec<64><<<MV_BLOCKS, 256, 0, stream>>>(agg_in, agg_in, W_agg, b_agg, xae, NN);
    const float* cur = xA;
    float* nxt = xB;
    for (int l = 0; l < LL; l++) {
        k_layer_agg<<<1024, 256, 0, stream>>>(cur, off, cnt, sorted, xagg);
        k_matvec<128><<<MV_BLOCKS, 256, 0, stream>>>(xagg, xae,
                                                     Wm + (size_t)l * 128 * 64, bm + l * 64,
                                                     mbuf, NN);
        k_matvec<128><<<MV_BLOCKS, 256, 0, stream>>>(cur, mbuf,
                                                     Wu + (size_t)l * 128 * 64, bu + l * 64,
                                                     nxt, NN);
        float* t = (float*)cur; cur = nxt; nxt = t;
    }
    int gs_waves = (NN + CHUNK - 1) / CHUNK;
    k_graph_sum<<<(gs_waves * 64 + 255) / 256, 256, 0, stream>>>(cur, batch, g_sum, g_cnt);
    k_graph_emb<<<16, 256, 0, stream>>>(g_sum, g_cnt, W_g, b_g, g_agg);
    k_readout<<<(NN + 255) / 256, 256, 0, stream>>>(g_agg, cur, batch, W_r, b_r, out);
}

// Round 3
// 1031.959 us; speedup vs baseline: 1.2966x; 1.1962x over previous
//
#include <hip/hip_runtime.h>

constexpr int NN  = 50000;
constexpr int EE  = 800000;
constexpr int GG  = 64;
constexpr int LL  = 3;

__device__ __forceinline__ float reluf(float x) { return x > 0.f ? x : 0.f; }

// ---------------- in-degree count --------------------------------------------
__global__ void k_count(const int* __restrict__ ei, int* __restrict__ cnt) {
    int e = blockIdx.x * blockDim.x + threadIdx.x;
    if (e >= EE) return;
    atomicAdd(&cnt[ei[EE + e]], 1);
}

// ------- parallel exclusive scan (49 blocks x 1024) + fused per-graph degmax -
__global__ void k_scan1(const int* __restrict__ cnt, int* __restrict__ off,
                        int* __restrict__ bsum,
                        const int* __restrict__ batch, const float* __restrict__ degree,
                        unsigned* __restrict__ degmax_u) {
    __shared__ int s[256];
    __shared__ unsigned smax[GG];
    int t = threadIdx.x, blk = blockIdx.x;
    if (t < GG) smax[t] = 0u;
    int base = blk * 1024 + t * 4;
    int v[4], tot = 0;
#pragma unroll
    for (int j = 0; j < 4; j++) {
        int i = base + j;
        v[j] = (i < NN) ? cnt[i] : 0;
        tot += v[j];
    }
    s[t] = tot;
    __syncthreads();
    // degmax: per-thread run compression (batch sorted), then LDS atomicMax
    {
        int curb = -1; unsigned cur = 0u;
#pragma unroll
        for (int j = 0; j < 4; j++) {
            int i = base + j;
            if (i < NN) {
                int b = batch[i];
                unsigned d = __float_as_uint(degree[i]);  // degree >= 0
                if (b != curb) {
                    if (curb >= 0) atomicMax(&smax[curb], cur);
                    curb = b; cur = d;
                } else if (d > cur) cur = d;
            }
        }
        if (curb >= 0) atomicMax(&smax[curb], cur);
    }
    for (int d = 1; d < 256; d <<= 1) {
        int a = (t >= d) ? s[t - d] : 0;
        __syncthreads();
        s[t] += a;
        __syncthreads();
    }
    int run = s[t] - tot;  // exclusive prefix within block
#pragma unroll
    for (int j = 0; j < 4; j++) {
        int i = base + j;
        if (i <= NN) off[i] = run;
        run += v[j];
    }
    if (t == 255) bsum[blk] = s[255];
    __syncthreads();
    if (t < GG && smax[t] != 0u) atomicMax(&degmax_u[t], smax[t]);
}
__global__ void k_scan2(int* __restrict__ bsum, int nb) {
    if (threadIdx.x == 0) {
        int run = 0;
        for (int b = 0; b < nb; b++) { int t = bsum[b]; bsum[b] = run; run += t; }
    }
}
__global__ void k_scan3(int* __restrict__ off, const int* __restrict__ bsum) {
    int i = blockIdx.x * blockDim.x + threadIdx.x;
    if (i <= NN) off[i] += bsum[i >> 10];
}

// ---------------- scatter edges into CSR order -------------------------------
__global__ void k_fill(const int* __restrict__ ei, const float* __restrict__ ea,
                       const int* __restrict__ off, int* __restrict__ fill,
                       int2* __restrict__ sorted) {
    int e = blockIdx.x * blockDim.x + threadIdx.x;
    if (e >= EE) return;
    int col = ei[e];
    int row = ei[EE + e];
    int p = off[row] + atomicAdd(&fill[row], 1);
    sorted[p] = make_int2(col, __float_as_int(ea[e]));
}

// ---------------- ne_sum from CSR (atomic-free): 8 lanes per node ------------
__global__ void k_nesum(const float* __restrict__ x, const int2* __restrict__ sorted,
                        const int* __restrict__ off, float* __restrict__ ne_sum) {
    int gwave = (blockIdx.x * blockDim.x + threadIdx.x) >> 6;
    int lane = threadIdx.x & 63;
    int sub = lane >> 3;   // 8 nodes per wave
    int f = lane & 7;      // 8 features (7 x + 1 ea)
    int node = gwave * 8 + sub;
    if (node >= NN) return;
    int jb = off[node], je = off[node + 1];
    float acc = 0.f;
    for (int j = jb; j < je; j++) {
        int2 p = sorted[j];
        acc += (f < 7) ? x[(size_t)p.x * 7 + f] : __int_as_float(p.y);
    }
    ne_sum[(size_t)node * 8 + f] = acc;
}

// ---------------- node pre: x_emb and agg_in = [relu(ne@W_ene+b), degnorm] ---
__global__ __launch_bounds__(256) void k_node_pre(
        const float* __restrict__ x, const int* __restrict__ cnt,
        const float* __restrict__ ne_sum, const unsigned* __restrict__ degmax_u,
        const int* __restrict__ batch,
        const float* __restrict__ W_en, const float* __restrict__ b_en,
        const float* __restrict__ W_ene, const float* __restrict__ b_ene,
        float* __restrict__ x_emb, float* __restrict__ agg_in) {
    __shared__ float sWen[7 * 64], sben[64];
    __shared__ float sWene[8 * 63], sbene[63];
    for (int i = threadIdx.x; i < 7 * 64; i += 256) sWen[i] = W_en[i];
    for (int i = threadIdx.x; i < 64; i += 256) sben[i] = b_en[i];
    for (int i = threadIdx.x; i < 8 * 63; i += 256) sWene[i] = W_ene[i];
    for (int i = threadIdx.x; i < 63; i += 256) sbene[i] = b_ene[i];
    __syncthreads();
    int lane = threadIdx.x & 63;
    int slot = threadIdx.x >> 6;
    int wave = blockIdx.x * 4 + slot;
    int nw = gridDim.x * 4;
    for (int i = wave; i < NN; i += nw) {
        float acc = sben[lane];
#pragma unroll
        for (int k = 0; k < 7; k++) acc += x[(size_t)i * 7 + k] * sWen[k * 64 + lane];
        x_emb[(size_t)i * 64 + lane] = reluf(acc);
        float c = (float)cnt[i]; if (c < 1.f) c = 1.f;
        float rc = 1.f / c;
        int oo = lane < 63 ? lane : 0;
        float na = sbene[oo];
#pragma unroll
        for (int k = 0; k < 8; k++) na += (ne_sum[(size_t)i * 8 + k] * rc) * sWene[k * 63 + oo];
        na = reluf(na);
        float dn = __uint_as_float(degmax_u[batch[i]]);
        agg_in[(size_t)i * 64 + lane] = (lane < 63) ? na : dn;
    }
}

// ---------------- matvec (K=64): out = relu(in @ W + b), lane = node ---------
__global__ __launch_bounds__(256) void k_matvec64(
        const float* __restrict__ inA,
        const float* __restrict__ W, const float* __restrict__ b,
        float* __restrict__ out, int n) {
    int gwave = (blockIdx.x * blockDim.x + threadIdx.x) >> 6;
    int lane = threadIdx.x & 63;
    int nwaves = (gridDim.x * blockDim.x) >> 6;
    int ntiles = ((n + 63) >> 6) * 2;
    for (int tile = gwave; tile < ntiles; tile += nwaves) {
        int base = (tile >> 1) * 64;
        int ohalf = tile & 1;
        int node = base + lane;
        bool valid = node < n;
        int nd = valid ? node : (n - 1);
        const float* pa = inA + (size_t)nd * 64;
        float acc[32];
#pragma unroll
        for (int o = 0; o < 32; o++) acc[o] = 0.f;
        for (int kb = 0; kb < 64; kb += 8) {
            float in[8];
            *(float4*)&in[0] = *(const float4*)(pa + kb);
            *(float4*)&in[4] = *(const float4*)(pa + kb + 4);
#pragma unroll
            for (int kk = 0; kk < 8; kk++) {
                const float* wr = W + (size_t)(kb + kk) * 64 + ohalf * 32;
#pragma unroll
                for (int o = 0; o < 32; o++)
                    acc[o] = fmaf(in[kk], wr[o], acc[o]);
            }
        }
        if (valid) {
            const float* bb = b + ohalf * 32;
            float* po = out + (size_t)nd * 64 + ohalf * 32;
            float4 r;
#pragma unroll
            for (int o = 0; o < 32; o += 4) {
                r.x = reluf(acc[o + 0] + bb[o + 0]);
                r.y = reluf(acc[o + 1] + bb[o + 1]);
                r.z = reluf(acc[o + 2] + bb[o + 2]);
                r.w = reluf(acc[o + 3] + bb[o + 3]);
                *(float4*)(po + o) = r;
            }
        }
    }
}

// ---------------- layer aggregation: x_agg = mean_j ea_j * xemb[col_j] -------
__global__ __launch_bounds__(256) void k_layer_agg(
        const float* __restrict__ xemb, const int* __restrict__ off,
        const int* __restrict__ cnt, const int2* __restrict__ sorted,
        float* __restrict__ xagg) {
    int lane = threadIdx.x & 63;
    int slot = threadIdx.x >> 6;
    int wave = blockIdx.x * 4 + slot;
    int nw = gridDim.x * 4;
    for (int i = wave; i < NN; i += nw) {
        int jb = off[i], je = off[i + 1];
        float acc = 0.f;
        for (int j = jb; j < je; j++) {
            int2 p = sorted[j];
            acc += __int_as_float(p.y) * xemb[(size_t)p.x * 64 + lane];
        }
        float c = (float)cnt[i]; if (c < 1.f) c = 1.f;
        xagg[(size_t)i * 64 + lane] = acc * (1.f / c);
    }
}

// ---------------- fused layer MLP --------------------------------------------
// m = relu([xagg|xae] @ Wm + bm);  xout = relu([xemb|m] @ Wu + bu)
// lane = node; m kept entirely in registers between the two matvecs.
__global__ __launch_bounds__(256, 2) void k_layer_mlp(
        const float* __restrict__ xemb, const float* __restrict__ xagg,
        const float* __restrict__ xae,
        const float* __restrict__ Wm, const float* __restrict__ bm,
        const float* __restrict__ Wu, const float* __restrict__ bu,
        float* __restrict__ xout) {
    int gwave = (blockIdx.x * blockDim.x + threadIdx.x) >> 6;
    int lane = threadIdx.x & 63;
    int nwaves = (gridDim.x * blockDim.x) >> 6;
    int ntiles = (NN + 63) >> 6;
    for (int tile = gwave; tile < ntiles; tile += nwaves) {
        int node = tile * 64 + lane;
        bool valid = node < NN;
        int nd = valid ? node : (NN - 1);
        float m[64];
#pragma unroll
        for (int o = 0; o < 64; o++) m[o] = 0.f;
        // phase 1a: xagg @ Wm[0:64]
        for (int kb = 0; kb < 64; kb += 8) {
            float in[8];
            *(float4*)&in[0] = *(const float4*)(xagg + (size_t)nd * 64 + kb);
            *(float4*)&in[4] = *(const float4*)(xagg + (size_t)nd * 64 + kb + 4);
#pragma unroll
            for (int kk = 0; kk < 8; kk++) {
                const float* wr = Wm + (size_t)(kb + kk) * 64;
#pragma unroll
                for (int o = 0; o < 64; o++) m[o] = fmaf(in[kk], wr[o], m[o]);
            }
        }
        // phase 1b: xae @ Wm[64:128]
        for (int kb = 0; kb < 64; kb += 8) {
            float in[8];
            *(float4*)&in[0] = *(const float4*)(xae + (size_t)nd * 64 + kb);
            *(float4*)&in[4] = *(const float4*)(xae + (size_t)nd * 64 + kb + 4);
#pragma unroll
            for (int kk = 0; kk < 8; kk++) {
                const float* wr = Wm + (size_t)(64 + kb + kk) * 64;
#pragma unroll
                for (int o = 0; o < 64; o++) m[o] = fmaf(in[kk], wr[o], m[o]);
            }
        }
#pragma unroll
        for (int o = 0; o < 64; o++) m[o] = reluf(m[o] + bm[o]);
        // phase 2a: xemb @ Wu[0:64]
        float u[64];
#pragma unroll
        for (int o = 0; o < 64; o++) u[o] = 0.f;
        for (int kb = 0; kb < 64; kb += 8) {
            float in[8];
            *(float4*)&in[0] = *(const float4*)(xemb + (size_t)nd * 64 + kb);
            *(float4*)&in[4] = *(const float4*)(xemb + (size_t)nd * 64 + kb + 4);
#pragma unroll
            for (int kk = 0; kk < 8; kk++) {
                const float* wr = Wu + (size_t)(kb + kk) * 64;
#pragma unroll
                for (int o = 0; o < 64; o++) u[o] = fmaf(in[kk], wr[o], u[o]);
            }
        }
        // phase 2b: m @ Wu[64:128] -- m is per-lane registers, fully unrolled
#pragma unroll
        for (int kk = 0; kk < 64; kk++) {
            const float* wr = Wu + (size_t)(64 + kk) * 64;
#pragma unroll
            for (int o = 0; o < 64; o++) u[o] = fmaf(m[kk], wr[o], u[o]);
        }
        if (valid) {
            float* po = xout + (size_t)nd * 64;
            float4 r;
#pragma unroll
            for (int o = 0; o < 64; o += 4) {
                r.x = reluf(u[o + 0] + bu[o + 0]);
                r.y = reluf(u[o + 1] + bu[o + 1]);
                r.z = reluf(u[o + 2] + bu[o + 2]);
                r.w = reluf(u[o + 3] + bu[o + 3]);
                *(float4*)(po + o) = r;
            }
        }
    }
}

// ---------------- graph mean (batch sorted: chunked accumulation) ------------
constexpr int CHUNK = 32;
__global__ void k_graph_sum(const float* __restrict__ xemb, const int* __restrict__ batch,
                            float* __restrict__ g_sum, int* __restrict__ g_cnt) {
    int wave = (blockIdx.x * blockDim.x + threadIdx.x) >> 6;
    int lane = threadIdx.x & 63;
    int i0 = wave * CHUNK;
    if (i0 >= NN) return;
    int i1 = i0 + CHUNK; if (i1 > NN) i1 = NN;
    int curb = batch[i0];
    float acc = 0.f;
    int ncnt = 0;
    for (int i = i0; i < i1; i++) {
        int b = batch[i];
        if (b != curb) {
            unsafeAtomicAdd(&g_sum[curb * 64 + lane], acc);
            if (lane == 0) atomicAdd(&g_cnt[curb], ncnt);
            acc = 0.f; ncnt = 0; curb = b;
        }
        acc += xemb[(size_t)i * 64 + lane];
        ncnt++;
    }
    unsafeAtomicAdd(&g_sum[curb * 64 + lane], acc);
    if (lane == 0) atomicAdd(&g_cnt[curb], ncnt);
}

// ---------------- graph embedding: g_agg = mean @ W_g + b_g (no relu) --------
__global__ void k_graph_emb(const float* __restrict__ g_sum, const int* __restrict__ g_cnt,
                            const float* __restrict__ W_g, const float* __restrict__ b_g,
                            float* __restrict__ g_agg) {
    __shared__ float sin[4 * 64];
    int lane = threadIdx.x & 63;
    int slot = threadIdx.x >> 6;
    int g = blockIdx.x * 4 + slot;
    if (g >= GG) return;
    float c = (float)g_cnt[g]; if (c < 1.f) c = 1.f;
    sin[slot * 64 + lane] = g_sum[g * 64 + lane] * (1.f / c);
    __syncthreads();
    float acc = b_g[lane];
    for (int k = 0; k < 64; k++) acc += sin[slot * 64 + k] * W_g[k * 64 + lane];
    g_agg[g * 64 + lane] = acc;
}

// ---------------- readout: q = relu([g_agg[batch], x_emb]) @ W_r + b_r -------
__global__ void k_readout(const float* __restrict__ g_agg, const float* __restrict__ xemb,
                          const int* __restrict__ batch,
                          const float* __restrict__ W_r, const float* __restrict__ b_r,
                          float* __restrict__ out) {
    int i = blockIdx.x * blockDim.x + threadIdx.x;
    if (i >= NN) return;
    int b = batch[i];
    float acc = b_r[0];
    const float* ga = g_agg + (size_t)b * 64;
    const float* xe = xemb + (size_t)i * 64;
#pragma unroll 8
    for (int k = 0; k < 64; k++) acc += reluf(ga[k]) * W_r[k];
#pragma unroll 8
    for (int k = 0; k < 64; k++) acc += reluf(xe[k]) * W_r[64 + k];
    out[i] = acc;
}

extern "C" void kernel_launch(void* const* d_in, const int* in_sizes, int n_in,
                              void* d_out, int out_size, void* d_ws, size_t ws_size,
                              hipStream_t stream) {
    const float* x      = (const float*)d_in[0];
    const int*   ei     = (const int*)d_in[1];
    const float* ea     = (const float*)d_in[2];
    const int*   batch  = (const int*)d_in[3];
    const float* degree = (const float*)d_in[4];
    const float* W_en  = (const float*)d_in[6];
    const float* b_en  = (const float*)d_in[7];
    const float* W_ene = (const float*)d_in[8];
    const float* b_ene = (const float*)d_in[9];
    const float* W_agg = (const float*)d_in[10];
    const float* b_agg = (const float*)d_in[11];
    const float* Wm    = (const float*)d_in[12];
    const float* bm    = (const float*)d_in[13];
    const float* Wu    = (const float*)d_in[14];
    const float* bu    = (const float*)d_in[15];
    const float* W_g   = (const float*)d_in[16];
    const float* b_g   = (const float*)d_in[17];
    const float* W_r   = (const float*)d_in[18];
    const float* b_r   = (const float*)d_in[19];
    float* out = (float*)d_out;

    // workspace layout (4B element offsets); zeroed region first
    char* ws = (char*)d_ws;
    size_t o = 0;
    int*      cnt      = (int*)(ws + o * 4);      o += NN;
    int*      fill     = (int*)(ws + o * 4);      o += NN;
    unsigned* degmax_u = (unsigned*)(ws + o * 4); o += GG;
    float*    g_sum    = (float*)(ws + o * 4);    o += GG * 64;
    int*      g_cnt    = (int*)(ws + o * 4);      o += GG;
    size_t zero_bytes = o * 4;
    int*      off      = (int*)(ws + o * 4);      o += NN + 1;
    int*      bsum     = (int*)(ws + o * 4);      o += 64;
    float*    ne_sum   = (float*)(ws + o * 4);    o += (size_t)NN * 8;
    o = (o + 1) & ~(size_t)1;  // 8B-align for int2
    int2*     sorted   = (int2*)(ws + o * 4);     o += (size_t)EE * 2;
    float*    agg_in   = (float*)(ws + o * 4);    o += (size_t)NN * 64;
    float*    xae      = (float*)(ws + o * 4);    o += (size_t)NN * 64;
    float*    xA       = (float*)(ws + o * 4);    o += (size_t)NN * 64;
    float*    xB       = (float*)(ws + o * 4);    o += (size_t)NN * 64;
    float*    xagg     = (float*)(ws + o * 4);    o += (size_t)NN * 64;
    float*    g_agg    = (float*)(ws + o * 4);    o += GG * 64;

    hipMemsetAsync(d_ws, 0, zero_bytes, stream);

    const int NB_SCAN = 49;  // ceil(50001/1024)
    k_count<<<(EE + 255) / 256, 256, 0, stream>>>(ei, cnt);
    k_scan1<<<NB_SCAN, 256, 0, stream>>>(cnt, off, bsum, batch, degree, degmax_u);
    k_scan2<<<1, 64, 0, stream>>>(bsum, NB_SCAN);
    k_scan3<<<(NN + 256) / 256, 256, 0, stream>>>(off, bsum);
    k_fill<<<(EE + 255) / 256, 256, 0, stream>>>(ei, ea, off, fill, sorted);
    k_nesum<<<((NN + 7) / 8 * 64 + 255) / 256, 256, 0, stream>>>(x, sorted, off, ne_sum);
    k_node_pre<<<512, 256, 0, stream>>>(x, cnt, ne_sum, degmax_u, batch,
                                        W_en, b_en, W_ene, b_ene, xA, agg_in);
    k_matvec64<<<391, 256, 0, stream>>>(agg_in, W_agg, b_agg, xae, NN);
    const float* cur = xA;
    float* nxt = xB;
    for (int l = 0; l < LL; l++) {
        k_layer_agg<<<1024, 256, 0, stream>>>(cur, off, cnt, sorted, xagg);
        k_layer_mlp<<<196, 256, 0, stream>>>(cur, xagg, xae,
                                             Wm + (size_t)l * 128 * 64, bm + l * 64,
                                             Wu + (size_t)l * 128 * 64, bu + l * 64,
                                             nxt);
        float* t = (float*)cur; cur = nxt; nxt = t;
    }
    int gs_waves = (NN + CHUNK - 1) / CHUNK;
    k_graph_sum<<<(gs_waves * 64 + 255) / 256, 256, 0, stream>>>(cur, batch, g_sum, g_cnt);
    k_graph_emb<<<16, 256, 0, stream>>>(g_sum, g_cnt, W_g, b_g, g_agg);
    k_readout<<<(NN + 255) / 256, 256, 0, stream>>>(g_agg, cur, batch, W_r, b_r, out);
}